// Round 11
// baseline (607.239 us; speedup 1.0000x reference)
//
#include <hip/hip_runtime.h>
#include <stdint.h>

#define AS1 __attribute__((address_space(1)))
#define AS3 __attribute__((address_space(3)))

typedef __bf16 bf16x8 __attribute__((ext_vector_type(8)));   // 4 VGPRs
typedef float  f32x4  __attribute__((ext_vector_type(4)));
typedef float  f32x16 __attribute__((ext_vector_type(16)));

#define MFMA16(a, b, c) __builtin_amdgcn_mfma_f32_16x16x32_bf16((a), (b), (c), 0, 0, 0)
#define MFMA32(a, b, c) __builtin_amdgcn_mfma_f32_32x32x16_bf16((a), (b), (c), 0, 0, 0)

// ---- constants for this problem ----
#define SEQ   512
#define NBAT  64
#define DM    768
#define NH    12
#define DH    64
#define NQKV  2304
#define NTOK  (NBAT * SEQ)   // 32768
#define NKB   12             // K=768 -> 12 K-tiles of 64

__device__ __forceinline__ uint16_t f2bf(float x) {          // fp32 -> bf16 RNE
  uint32_t u = __float_as_uint(x);
  return (uint16_t)((u + 0x7FFFu + ((u >> 16) & 1u)) >> 16);
}

__device__ __forceinline__ void async16(uint16_t* lds, const uint16_t* g) {
  // 16B global -> LDS direct (dest = wave-uniform base + lane*16)
  __builtin_amdgcn_global_load_lds((AS1 void*)(uintptr_t)(const void*)g,
                                   (AS3 void*)lds, 16, 0, 0);
}

// row->column XOR swizzle: conflict-free for the MFMA fragment reads below
// (measured 0 SQ_LDS_BANK_CONFLICT on the GEMM).
__device__ __forceinline__ int swz(int r) { return (r ^ (r >> 3)) & 7; }

// ---------------- merged converter + weight fragment-packing ----------------
__global__ __launch_bounds__(256) void k_cvt(
    const float* __restrict__ tokens,
    const float* __restrict__ Wq, const float* __restrict__ Wk,
    const float* __restrict__ Wv, const float* __restrict__ Wo,
    const float* __restrict__ bq, const float* __restrict__ bk, const float* __restrict__ bv,
    uint16_t* __restrict__ X, uint16_t* __restrict__ Wqkv_pk, uint16_t* __restrict__ Wob_pk,
    float* __restrict__ bqkv) {
  int i = blockIdx.x * 256 + threadIdx.x;     // grid covers NTOK*DM/8 = 3,145,728
  {
    const float4* sp = (const float4*)tokens;
    float4 a = sp[2 * i], b = sp[2 * i + 1];
    union { uint16_t u[8]; uint4 v; } o;
    o.u[0] = f2bf(a.x); o.u[1] = f2bf(a.y); o.u[2] = f2bf(a.z); o.u[3] = f2bf(a.w);
    o.u[4] = f2bf(b.x); o.u[5] = f2bf(b.y); o.u[6] = f2bf(b.z); o.u[7] = f2bf(b.w);
    ((uint4*)X)[i] = o.v;
  }
  // Wqkv pack: 2304*768/8 = 221184 chunks
  if (i < 221184) {
    int lane = i & 63, ks = (i >> 6) & 3, kb = (i >> 8) % NKB, g = i / 3072;
    int row = g * 32 + (lane & 31);
    int k   = kb * 64 + ks * 16 + (lane >> 5) * 8;
    const float* src = (row < 768)  ? Wq + (size_t)row * 768 + k
                     : (row < 1536) ? Wk + (size_t)(row - 768) * 768 + k
                                    : Wv + (size_t)(row - 1536) * 768 + k;
    float4 a = *(const float4*)src, b = *(const float4*)(src + 4);
    union { uint16_t u[8]; uint4 v; } o;
    o.u[0] = f2bf(a.x); o.u[1] = f2bf(a.y); o.u[2] = f2bf(a.z); o.u[3] = f2bf(a.w);
    o.u[4] = f2bf(b.x); o.u[5] = f2bf(b.y); o.u[6] = f2bf(b.z); o.u[7] = f2bf(b.w);
    ((uint4*)Wqkv_pk)[i] = o.v;
  }
  // Wo pack: 768*768/8 = 73728 chunks
  if (i < 73728) {
    int lane = i & 63, ks = (i >> 6) & 3, kb = (i >> 8) % NKB, g = i / 3072;
    int row = g * 32 + (lane & 31);
    int k   = kb * 64 + ks * 16 + (lane >> 5) * 8;
    const float* src = Wo + (size_t)row * 768 + k;
    float4 a = *(const float4*)src, b = *(const float4*)(src + 4);
    union { uint16_t u[8]; uint4 v; } o;
    o.u[0] = f2bf(a.x); o.u[1] = f2bf(a.y); o.u[2] = f2bf(a.z); o.u[3] = f2bf(a.w);
    o.u[4] = f2bf(b.x); o.u[5] = f2bf(b.y); o.u[6] = f2bf(b.z); o.u[7] = f2bf(b.w);
    ((uint4*)Wob_pk)[i] = o.v;
  }
  if (i < 768) { bqkv[i] = bq[i]; bqkv[i + 768] = bk[i]; bqkv[i + 1536] = bv[i]; }
}

// ---------------- GEMM (R8-proven: ~147us, occ 41%, 0 conflicts) ----------------
__global__ __launch_bounds__(256, 4) void k_gemm_bt(
    const uint16_t* __restrict__ A, const uint16_t* __restrict__ Bpk,
    const float* __restrict__ bias, const float* __restrict__ rowscale,
    uint16_t* __restrict__ C, int ldc, int ncol) {
  __shared__ uint16_t Alds[128 * 64];   // 16 KB
  const int tid  = threadIdx.x;
  const int w    = tid >> 6, lane = tid & 63;
  const int wu   = __builtin_amdgcn_readfirstlane(w);
  const int l32  = lane & 31, kh = lane >> 5;
  const int sup  = blockIdx.x / (32 * ncol);
  const int t    = blockIdx.x % (32 * ncol);
  const int row0 = (sup * 32 + (t & 31)) * 128, col0 = (t >> 5) * 128;
  const int wrow = (w >> 1) * 64,   wcol = (w & 1) * 64;

  const uint16_t* bw = Bpk + (size_t)((col0 >> 5) + (w & 1) * 2) * (NKB * 2048) + lane * 8;

  f32x16 acc[2][2] = {};
  for (int kb = 0; kb < NKB; ++kb) {
    __syncthreads();                              // prev iter's A-frag reads done
#pragma unroll
    for (int j = 0; j < 4; ++j) {                 // A: 1024 chunks
      int cid = j * 256 + w * 64 + lane;
      int r = cid >> 3, cc = cid & 7, c = cc ^ swz(r);
      async16(&Alds[(j * 256 + wu * 64) * 8],
              A + (size_t)(row0 + r) * 768 + kb * 64 + c * 8);
    }
    __syncthreads();                              // staging drained
#pragma unroll
    for (int ks = 0; ks < 4; ++ks) {              // 4 k-steps of 16
      bf16x8 bfr[2];
#pragma unroll
      for (int nt = 0; nt < 2; ++nt)
        bfr[nt] = *(const bf16x8*)(bw + (size_t)nt * (NKB * 2048) + (kb * 4 + ks) * 512);
      bf16x8 af[2];
#pragma unroll
      for (int mt = 0; mt < 2; ++mt) {
        int r = wrow + mt * 32 + l32;
        int c = (ks * 2 + kh) ^ swz(r);
        af[mt] = *(const bf16x8*)&Alds[r * 64 + c * 8];
      }
#pragma unroll
      for (int mt = 0; mt < 2; ++mt)
#pragma unroll
        for (int nt = 0; nt < 2; ++nt)
          acc[mt][nt] = MFMA32(af[mt], bfr[nt], acc[mt][nt]);
    }
  }
#pragma unroll
  for (int nt = 0; nt < 2; ++nt) {
    int col = col0 + wcol + nt * 32 + l32;
    float bv = bias[col];
#pragma unroll
    for (int mt = 0; mt < 2; ++mt) {
#pragma unroll
      for (int rg = 0; rg < 16; ++rg) {
        int row = row0 + wrow + mt * 32 + (rg & 3) + 8 * (rg >> 2) + 4 * kh;
        float v = acc[mt][nt][rg] + bv;
        if (rowscale) v *= rowscale[row];
        C[(size_t)row * ldc + col] = f2bf(v);
      }
    }
  }
}

// ---------------- fused attention: R11 swapped-QK^T, in-register softmax ----------------
// S^T = mfma(A=K, B=Q): lane holds P[k = km*16+quad*4+rg][q = l16] for one q.
// Softmax is register-only (tq scalar/lane, tk float4 from tkl, row-sum
// deferred to an epilogue shfl_xor reduce) — no Plds, no ones-MFMA.
// PV B-fragment built by 16 __shfl + 4 selects per kt (target (l16,quad t)
// needs k=8t+j; source lane = l16+32(t&1) [+16], word w[t>>1][j>>1];
// km*16+sq*4 = 8t identity). PV = mfma(A=V, B=P); accO lane-holds
// O[q=l16][d=dt*16+quad*4+rg] -> 8B vector epilogue stores.
// Plds deleted -> LDS 36KB; Vt double-buffered -> ONE barrier per tile
// (it drains K gload_lds vmcnt + Vt ds_write lgkm together).
__global__ __launch_bounds__(512, 4) void k_attn(
    const uint16_t* __restrict__ QKV, const float* __restrict__ ts,
    const float* __restrict__ mask, uint16_t* __restrict__ Aout) {
  __shared__ uint16_t Klds[2][64 * 64];       // swizzled chunks, 2 x 8KB
  __shared__ uint16_t Vt[2][64 * 72];         // [d][k] padded, 2 x 9KB
  __shared__ float tkl[SEQ];                  // ts*c2, masked -> +3e38  (2KB)

  const int tid = threadIdx.x, w = tid >> 6, lane = tid & 63;
  const int wu = __builtin_amdgcn_readfirstlane(w);
  const int quad = lane >> 4, l16 = lane & 15;
  int b = blockIdx.x;
  int xcd = b & 7, i = b >> 3;               // i: 0..191
  int qtp = i & 1;                           // q-tile pair
  int hg = xcd * 96 + (i >> 1);              // 0..767
  int n = hg / NH, h = hg % NH;
  const int q0 = (qtp * 2 + (w >> 2)) * 128 + (w & 3) * 32;
  const size_t rowbase = (size_t)n * SEQ * NQKV;

  const float c1 = 0.125f * 1.44269504f;     // scale * log2(e)
  const float c2 = 1.44269504f / 300.0f;     // log2(e) / tau

  for (int l = tid; l < SEQ; l += 512) {
    float t = ts[n * SEQ + l] * c2;
    tkl[l] = (mask[n * SEQ + l] > 0.f) ? t : 3e38f;
  }

  // Q fragments (B-operand; layout identical to A: [n=l16][d=quad*8+j])
  bf16x8 qf[2][2];
  float tq[2];
#pragma unroll
  for (int qs = 0; qs < 2; ++qs) {
    int qr = q0 + qs * 16 + l16;
    const uint16_t* qp = QKV + rowbase + (size_t)qr * NQKV + h * DH;
#pragma unroll
    for (int dsp = 0; dsp < 2; ++dsp)
      qf[qs][dsp] = *(const bf16x8*)(qp + dsp * 32 + quad * 8);
    tq[qs] = ts[n * SEQ + qr] * c2;
  }

  f32x4 accO[2][4] = {};     // [qs][dt]: O[q=l16][d=dt*16+quad*4+rg]
  float accL[2] = {0.f, 0.f};

  const uint16_t* Kbase = QKV + rowbase + DM + h * DH;
  const uint16_t* Vbase = QKV + rowbase + 2 * DM + h * DH;
  const int vr = tid & 63, vdb = (tid >> 6) * 8;   // 8 d-cols per thread
  const int kr = tid >> 3, kc = (tid & 7) ^ swz(tid >> 3);
  const int sA = l16 + ((quad & 1) << 5);          // shuffle src lanes
  const int sB = sA + 16;
  uint4 vreg0;

  // prologue: stage tile 0
  async16(&Klds[0][wu * 64 * 8], Kbase + (size_t)kr * NQKV + kc * 8);
  vreg0 = *(const uint4*)(Vbase + (size_t)vr * NQKV + vdb);
  __syncthreads();                           // K0 landed; vreg ready; tkl visible
  {
    union { uint4 v; uint16_t u[8]; } a0;
    a0.v = vreg0;
#pragma unroll
    for (int j = 0; j < 8; ++j) Vt[0][(vdb + j) * 72 + vr] = a0.u[j];
  }
  __syncthreads();                           // tile 0 ready

  for (int it = 0; it < 8; ++it) {
    const int k0 = it * 64, cur = it & 1;
    // prefetch tile it+1 BEFORE compute
    if (it < 7) {
      async16(&Klds[cur ^ 1][wu * 64 * 8],
              Kbase + (size_t)(k0 + 64 + kr) * NQKV + kc * 8);
      vreg0 = *(const uint4*)(Vbase + (size_t)(k0 + 64 + vr) * NQKV + vdb);
    }

#pragma unroll
    for (int kt = 0; kt < 2; ++kt) {
      // S^T: A = K rows (m = key idx), B = Q rows (n = q), contraction = d
      f32x4 s[2][2] = {};                    // [qs][km]
      __builtin_amdgcn_s_setprio(1);
#pragma unroll
      for (int dsp = 0; dsp < 2; ++dsp) {
        bf16x8 kfA[2];
#pragma unroll
        for (int km = 0; km < 2; ++km) {
          int r = kt * 32 + km * 16 + l16;
          int c = (dsp * 4 + quad) ^ swz(r);
          kfA[km] = *(const bf16x8*)&Klds[cur][r * 64 + c * 8];
        }
#pragma unroll
        for (int qs = 0; qs < 2; ++qs)
#pragma unroll
          for (int km = 0; km < 2; ++km)
            s[qs][km] = MFMA16(kfA[km], qf[qs][dsp], s[qs][km]);
      }
      __builtin_amdgcn_s_setprio(0);

      // time-decay keys for this kt (4 consecutive per km)
      float4 tka = *(const float4*)&tkl[k0 + kt * 32 + quad * 4];
      float4 tkb = *(const float4*)&tkl[k0 + kt * 32 + 16 + quad * 4];

      // V fragments (A-operand): V[d = dt*16+l16][k = kt*32+quad*8+j]
      bf16x8 vb[4];
#pragma unroll
      for (int dt = 0; dt < 4; ++dt)
        vb[dt] = *(const bf16x8*)&Vt[cur][(dt * 16 + l16) * 72 + kt * 32 + quad * 8];

#pragma unroll
      for (int qs = 0; qs < 2; ++qs) {
        float tqv = tq[qs];
        float p00 = __builtin_amdgcn_exp2f(fmaf(s[qs][0][0], c1, -fabsf(tqv - tka.x)));
        float p01 = __builtin_amdgcn_exp2f(fmaf(s[qs][0][1], c1, -fabsf(tqv - tka.y)));
        float p02 = __builtin_amdgcn_exp2f(fmaf(s[qs][0][2], c1, -fabsf(tqv - tka.z)));
        float p03 = __builtin_amdgcn_exp2f(fmaf(s[qs][0][3], c1, -fabsf(tqv - tka.w)));
        float p10 = __builtin_amdgcn_exp2f(fmaf(s[qs][1][0], c1, -fabsf(tqv - tkb.x)));
        float p11 = __builtin_amdgcn_exp2f(fmaf(s[qs][1][1], c1, -fabsf(tqv - tkb.y)));
        float p12 = __builtin_amdgcn_exp2f(fmaf(s[qs][1][2], c1, -fabsf(tqv - tkb.z)));
        float p13 = __builtin_amdgcn_exp2f(fmaf(s[qs][1][3], c1, -fabsf(tqv - tkb.w)));
        accL[qs] += (p00 + p01 + p02 + p03) + (p10 + p11 + p12 + p13);
        // pack (truncate, as before): w[km][0] = (p0,p1), w[km][1] = (p2,p3)
        uint32_t w00 = (__float_as_uint(p00) >> 16) | (__float_as_uint(p01) & 0xFFFF0000u);
        uint32_t w01 = (__float_as_uint(p02) >> 16) | (__float_as_uint(p03) & 0xFFFF0000u);
        uint32_t w10 = (__float_as_uint(p10) >> 16) | (__float_as_uint(p11) & 0xFFFF0000u);
        uint32_t w11 = (__float_as_uint(p12) >> 16) | (__float_as_uint(p13) & 0xFFFF0000u);
        // redistribute: target (l16, quad t) B-frag k = 8t+j
        uint32_t a0 = __shfl(w00, sA, 64), a1 = __shfl(w01, sA, 64);
        uint32_t b0 = __shfl(w00, sB, 64), b1 = __shfl(w01, sB, 64);
        uint32_t c0 = __shfl(w10, sA, 64), c1r = __shfl(w11, sA, 64);
        uint32_t d0 = __shfl(w10, sB, 64), d1 = __shfl(w11, sB, 64);
        bool lo = quad < 2;                  // km_needed = quad>>1
        union { uint32_t u[4]; bf16x8 v; } pa;
        pa.u[0] = lo ? a0 : c0;
        pa.u[1] = lo ? a1 : c1r;
        pa.u[2] = lo ? b0 : d0;
        pa.u[3] = lo ? b1 : d1;
        // PV: A = V-frag, B = P-frag
        __builtin_amdgcn_s_setprio(1);
#pragma unroll
        for (int dt = 0; dt < 4; ++dt)
          accO[qs][dt] = MFMA16(vb[dt], pa.v, accO[qs][dt]);
        __builtin_amdgcn_s_setprio(0);
      }
    }

    // V(t+1) reg -> LDS (other buffer; disjoint from this tile's reads)
    if (it < 7) {
      union { uint4 v; uint16_t u[8]; } a0;
      a0.v = vreg0;
#pragma unroll
      for (int j = 0; j < 8; ++j) Vt[cur ^ 1][(vdb + j) * 72 + vr] = a0.u[j];
    }
    __syncthreads();   // drains K(t+1) vmcnt + Vt(t+1) lgkm; joins waves
  }

  // epilogue: row-sum reduce across quads, then O = accO / l, 8B stores
#pragma unroll
  for (int qs = 0; qs < 2; ++qs) {
    float l = accL[qs];
    l += __shfl_xor(l, 16, 64);
    l += __shfl_xor(l, 32, 64);
    float inv = 1.0f / l;
    int qr = q0 + qs * 16 + l16;
    uint16_t* op = Aout + (size_t)(n * SEQ + qr) * DM + h * DH + quad * 4;
#pragma unroll
    for (int dt = 0; dt < 4; ++dt) {
      union { uint16_t u[4]; uint2 d; } o;
#pragma unroll
      for (int rg = 0; rg < 4; ++rg) o.u[rg] = f2bf(accO[qs][dt][rg] * inv);
      *(uint2*)(op + dt * 16) = o.d;
    }
  }
}

// ---------------- readout pooling (unchanged) ----------------
__global__ __launch_bounds__(256) void k_pool(
    const uint16_t* __restrict__ Out, const float* __restrict__ mask,
    const float* __restrict__ readout, float* __restrict__ dst) {
  __shared__ float rsl[64];
  __shared__ float ex[SEQ];
  __shared__ float red[4];
  __shared__ float part[8][64];
  int b = blockIdx.x;
  int n = b / NH, h = b % NH;
  int tid = threadIdx.x;
  if (tid < 64) rsl[tid] = readout[h * DH + tid];
  __syncthreads();

  float suml = 0.f;
  for (int l = tid; l < SEQ; l += 256) {
    const uint16_t* rowp = Out + (size_t)(n * SEQ + l) * DM + h * DH;
    float acc = 0.f;
#pragma unroll
    for (int c = 0; c < 8; ++c) {
      union { uint4 v; uint16_t u[8]; } t;
      t.v = *(const uint4*)(rowp + c * 8);
#pragma unroll
      for (int j = 0; j < 8; ++j)
        acc += __uint_as_float(((uint32_t)t.u[j]) << 16) * rsl[c * 8 + j];
    }
    float e = __builtin_amdgcn_exp2f(acc * (0.125f * 1.44269504f));
    e = (mask[n * SEQ + l] > 0.f) ? e : 0.f;
    ex[l] = e;
    suml += e;
  }
#pragma unroll
  for (int off = 32; off; off >>= 1) suml += __shfl_down(suml, off, 64);
  if ((tid & 63) == 0) red[tid >> 6] = suml;
  __syncthreads();
  float inv = 1.0f / (red[0] + red[1] + red[2] + red[3]);

  int d0 = (tid & 31) * 2, ch = tid >> 5;
  float a0 = 0.f, a1 = 0.f;
  for (int l = ch * 64; l < ch * 64 + 64; ++l) {
    uint32_t pv = *(const uint32_t*)(Out + (size_t)(n * SEQ + l) * DM + h * DH + d0);
    float e = ex[l];
    a0 = fmaf(__uint_as_float(pv << 16), e, a0);
    a1 = fmaf(__uint_as_float(pv & 0xFFFF0000u), e, a1);
  }
  part[ch][d0] = a0;
  part[ch][d0 + 1] = a1;
  __syncthreads();
  if (tid < 64) {
    float s = 0.f;
#pragma unroll
    for (int c = 0; c < 8; ++c) s += part[c][tid];
    dst[n * DM + h * DH + tid] = s * inv;
  }
}

// ---------------- launch ----------------
extern "C" void kernel_launch(void* const* d_in, const int* in_sizes, int n_in,
                              void* d_out, int out_size, void* d_ws, size_t ws_size,
                              hipStream_t stream) {
  const float* tokens  = (const float*)d_in[0];
  const float* ts      = (const float*)d_in[1];
  const float* mask    = (const float*)d_in[2];
  const float* Wq      = (const float*)d_in[3];
  const float* bq      = (const float*)d_in[4];
  const float* Wk      = (const float*)d_in[5];
  const float* bk      = (const float*)d_in[6];
  const float* Wv      = (const float*)d_in[7];
  const float* bv      = (const float*)d_in[8];
  const float* Wo      = (const float*)d_in[9];
  const float* bo      = (const float*)d_in[10];
  const float* readout = (const float*)d_in[11];

  char* ws = (char*)d_ws;
  uint16_t* X    = (uint16_t*)ws;                   // 50,331,648 B ; reused as attn_out
  uint16_t* Wqkv = (uint16_t*)(ws + 50331648);      //  3,538,944 B (packed)
  uint16_t* Wob  = (uint16_t*)(ws + 53870592);      //  1,179,648 B (packed)
  float*    bqkv = (float*)   (ws + 55050240);      //      9,216 B
  uint16_t* QKV  = (uint16_t*)(ws + 55059456);      // 150,994,944 B ; reused as Out
  uint16_t* attn = X;
  uint16_t* Outb = QKV;

  k_cvt<<<12288, 256, 0, stream>>>(tokens, Wq, Wk, Wv, Wo, bq, bk, bv, X, Wqkv, Wob, bqkv);
  k_gemm_bt<<<4608, 256, 0, stream>>>(X, Wqkv, bqkv, nullptr, QKV, NQKV, 18);
  k_attn<<<1536, 512, 0, stream>>>(QKV, ts, mask, attn);
  k_gemm_bt<<<1536, 256, 0, stream>>>(attn, Wob, bo, mask, Outb, DM, 6);
  k_pool<<<768, 256, 0, stream>>>(Outb, mask, readout, (float*)d_out);
}

// Round 12
// 466.125 us; speedup vs baseline: 1.3027x; 1.3027x over previous
//
#include <hip/hip_runtime.h>
#include <stdint.h>

#define AS1 __attribute__((address_space(1)))
#define AS3 __attribute__((address_space(3)))

typedef __bf16 bf16x8 __attribute__((ext_vector_type(8)));   // 4 VGPRs
typedef float  f32x4  __attribute__((ext_vector_type(4)));
typedef float  f32x16 __attribute__((ext_vector_type(16)));

#define MFMA16(a, b, c) __builtin_amdgcn_mfma_f32_16x16x32_bf16((a), (b), (c), 0, 0, 0)
#define MFMA32(a, b, c) __builtin_amdgcn_mfma_f32_32x32x16_bf16((a), (b), (c), 0, 0, 0)

// ---- constants for this problem ----
#define SEQ   512
#define NBAT  64
#define DM    768
#define NH    12
#define DH    64
#define NQKV  2304
#define NTOK  (NBAT * SEQ)   // 32768
#define NKB   12             // K=768 -> 12 K-tiles of 64

__device__ __forceinline__ uint16_t f2bf(float x) {          // fp32 -> bf16 RNE
  uint32_t u = __float_as_uint(x);
  return (uint16_t)((u + 0x7FFFu + ((u >> 16) & 1u)) >> 16);
}

__device__ __forceinline__ void async16(uint16_t* lds, const uint16_t* g) {
  // 16B global -> LDS direct (dest = wave-uniform base + lane*16)
  __builtin_amdgcn_global_load_lds((AS1 void*)(uintptr_t)(const void*)g,
                                   (AS3 void*)lds, 16, 0, 0);
}

// row->column XOR swizzle: conflict-free for the 32-row (l32/kh-split) MFMA
// fragment reads used below (measured 0 SQ_LDS_BANK_CONFLICT).
__device__ __forceinline__ int swz(int r) { return (r ^ (r >> 3)) & 7; }

// ---------------- merged converter + weight fragment-packing ----------------
__global__ __launch_bounds__(256) void k_cvt(
    const float* __restrict__ tokens,
    const float* __restrict__ Wq, const float* __restrict__ Wk,
    const float* __restrict__ Wv, const float* __restrict__ Wo,
    const float* __restrict__ bq, const float* __restrict__ bk, const float* __restrict__ bv,
    uint16_t* __restrict__ X, uint16_t* __restrict__ Wqkv_pk, uint16_t* __restrict__ Wob_pk,
    float* __restrict__ bqkv) {
  int i = blockIdx.x * 256 + threadIdx.x;     // grid covers NTOK*DM/8 = 3,145,728
  {
    const float4* sp = (const float4*)tokens;
    float4 a = sp[2 * i], b = sp[2 * i + 1];
    union { uint16_t u[8]; uint4 v; } o;
    o.u[0] = f2bf(a.x); o.u[1] = f2bf(a.y); o.u[2] = f2bf(a.z); o.u[3] = f2bf(a.w);
    o.u[4] = f2bf(b.x); o.u[5] = f2bf(b.y); o.u[6] = f2bf(b.z); o.u[7] = f2bf(b.w);
    ((uint4*)X)[i] = o.v;
  }
  // Wqkv pack: 2304*768/8 = 221184 chunks
  if (i < 221184) {
    int lane = i & 63, ks = (i >> 6) & 3, kb = (i >> 8) % NKB, g = i / 3072;
    int row = g * 32 + (lane & 31);
    int k   = kb * 64 + ks * 16 + (lane >> 5) * 8;
    const float* src = (row < 768)  ? Wq + (size_t)row * 768 + k
                     : (row < 1536) ? Wk + (size_t)(row - 768) * 768 + k
                                    : Wv + (size_t)(row - 1536) * 768 + k;
    float4 a = *(const float4*)src, b = *(const float4*)(src + 4);
    union { uint16_t u[8]; uint4 v; } o;
    o.u[0] = f2bf(a.x); o.u[1] = f2bf(a.y); o.u[2] = f2bf(a.z); o.u[3] = f2bf(a.w);
    o.u[4] = f2bf(b.x); o.u[5] = f2bf(b.y); o.u[6] = f2bf(b.z); o.u[7] = f2bf(b.w);
    ((uint4*)Wqkv_pk)[i] = o.v;
  }
  // Wo pack: 768*768/8 = 73728 chunks
  if (i < 73728) {
    int lane = i & 63, ks = (i >> 6) & 3, kb = (i >> 8) % NKB, g = i / 3072;
    int row = g * 32 + (lane & 31);
    int k   = kb * 64 + ks * 16 + (lane >> 5) * 8;
    const float* src = Wo + (size_t)row * 768 + k;
    float4 a = *(const float4*)src, b = *(const float4*)(src + 4);
    union { uint16_t u[8]; uint4 v; } o;
    o.u[0] = f2bf(a.x); o.u[1] = f2bf(a.y); o.u[2] = f2bf(a.z); o.u[3] = f2bf(a.w);
    o.u[4] = f2bf(b.x); o.u[5] = f2bf(b.y); o.u[6] = f2bf(b.z); o.u[7] = f2bf(b.w);
    ((uint4*)Wob_pk)[i] = o.v;
  }
  if (i < 768) { bqkv[i] = bq[i]; bqkv[i + 768] = bk[i]; bqkv[i + 1536] = bv[i]; }
}

// ---------------- GEMM (R8-proven: ~147us, occ 41%, 0 conflicts) ----------------
__global__ __launch_bounds__(256, 4) void k_gemm_bt(
    const uint16_t* __restrict__ A, const uint16_t* __restrict__ Bpk,
    const float* __restrict__ bias, const float* __restrict__ rowscale,
    uint16_t* __restrict__ C, int ldc, int ncol) {
  __shared__ uint16_t Alds[128 * 64];   // 16 KB
  const int tid  = threadIdx.x;
  const int w    = tid >> 6, lane = tid & 63;
  const int wu   = __builtin_amdgcn_readfirstlane(w);
  const int l32  = lane & 31, kh = lane >> 5;
  const int sup  = blockIdx.x / (32 * ncol);
  const int t    = blockIdx.x % (32 * ncol);
  const int row0 = (sup * 32 + (t & 31)) * 128, col0 = (t >> 5) * 128;
  const int wrow = (w >> 1) * 64,   wcol = (w & 1) * 64;

  // packed-B base for this wave: group g0 = col0/32 + (w&1)*2; +nt advances one group.
  const uint16_t* bw = Bpk + (size_t)((col0 >> 5) + (w & 1) * 2) * (NKB * 2048) + lane * 8;

  f32x16 acc[2][2] = {};
  for (int kb = 0; kb < NKB; ++kb) {
    __syncthreads();                              // prev iter's A-frag reads done
#pragma unroll
    for (int j = 0; j < 4; ++j) {                 // A: 1024 chunks
      int cid = j * 256 + w * 64 + lane;
      int r = cid >> 3, cc = cid & 7, c = cc ^ swz(r);
      async16(&Alds[(j * 256 + wu * 64) * 8],
              A + (size_t)(row0 + r) * 768 + kb * 64 + c * 8);
    }
    __syncthreads();                              // staging drained
#pragma unroll
    for (int ks = 0; ks < 4; ++ks) {              // 4 k-steps of 16
      // B fragments for this k-step: 2 contiguous 16B loads (L2 hits)
      bf16x8 bfr[2];
#pragma unroll
      for (int nt = 0; nt < 2; ++nt)
        bfr[nt] = *(const bf16x8*)(bw + (size_t)nt * (NKB * 2048) + (kb * 4 + ks) * 512);
      bf16x8 af[2];
#pragma unroll
      for (int mt = 0; mt < 2; ++mt) {
        int r = wrow + mt * 32 + l32;
        int c = (ks * 2 + kh) ^ swz(r);
        af[mt] = *(const bf16x8*)&Alds[r * 64 + c * 8];
      }
#pragma unroll
      for (int mt = 0; mt < 2; ++mt)
#pragma unroll
        for (int nt = 0; nt < 2; ++nt)
          acc[mt][nt] = MFMA32(af[mt], bfr[nt], acc[mt][nt]);
    }
  }
  // epilogue: 32x32 C/D layout: col=lane&31, row=(reg&3)+8*(reg>>2)+4*(lane>>5)
#pragma unroll
  for (int nt = 0; nt < 2; ++nt) {
    int col = col0 + wcol + nt * 32 + l32;
    float bv = bias[col];
#pragma unroll
    for (int mt = 0; mt < 2; ++mt) {
#pragma unroll
      for (int rg = 0; rg < 16; ++rg) {
        int row = row0 + wrow + mt * 32 + (rg & 3) + 8 * (rg >> 2) + 4 * kh;
        float v = acc[mt][nt][rg] + bv;
        if (rowscale) v *= rowscale[row];
        C[(size_t)row * ldc + col] = f2bf(v);
      }
    }
  }
}

// ---------------- fused attention: R10 = R9 qt-merge + K double-buffer, no fences ----------------
// Per tile t: K(t+1) gload_lds -> Klds[cur^1] AND V(t+1)->reg issued BEFORE
// compute(t), so the barrier's vmcnt drain has a full compute phase of cover.
// WAR: Klds[cur^1] was last read in it-1's compute, two barriers before the
// re-issue. P-write->read order is preserved by may-alias + the in-order DS
// pipe (R0-proven). Best measured attn: ~83us (near its HBM traffic floor).
__global__ __launch_bounds__(512) void k_attn(
    const uint16_t* __restrict__ QKV, const float* __restrict__ ts,
    const float* __restrict__ mask, uint16_t* __restrict__ Aout) {
  __shared__ uint16_t Klds[2][64 * 64];       // swizzled chunks, 2 x 8KB
  __shared__ uint16_t Vt[64 * 72];            // [d][k] padded, 9KB
  __shared__ uint16_t Plds[8][2 * 32 * 40];   // per-wave, kt-indexed, 40KB
  __shared__ float tkl[SEQ];                  // ts*c2, masked -> +3e38

  const int tid = threadIdx.x, w = tid >> 6, lane = tid & 63;
  const int wu = __builtin_amdgcn_readfirstlane(w);
  const int quad = lane >> 4, l16 = lane & 15;
  int b = blockIdx.x;
  int xcd = b & 7, i = b >> 3;               // i: 0..191
  int qtp = i & 1;                           // q-tile pair
  int hg = xcd * 96 + (i >> 1);              // 0..767
  int n = hg / NH, h = hg % NH;
  const int q0 = (qtp * 2 + (w >> 2)) * 128 + (w & 3) * 32;
  const size_t rowbase = (size_t)n * SEQ * NQKV;

  const float c1 = 0.125f * 1.44269504f;     // scale * log2(e)
  const float c2 = 1.44269504f / 300.0f;     // log2(e) / tau

  for (int l = tid; l < SEQ; l += 512) {
    float t = ts[n * SEQ + l] * c2;
    tkl[l] = (mask[n * SEQ + l] > 0.f) ? t : 3e38f;
  }

  // Q fragments (A-operand): A[m=lane&15][k=quad*8+j]
  bf16x8 qf[2][2];
  float tq[2][4];
#pragma unroll
  for (int qs = 0; qs < 2; ++qs) {
    int qr = q0 + qs * 16 + l16;
    const uint16_t* qp = QKV + rowbase + (size_t)qr * NQKV + h * DH;
#pragma unroll
    for (int dsp = 0; dsp < 2; ++dsp)
      qf[qs][dsp] = *(const bf16x8*)(qp + dsp * 32 + quad * 8);
#pragma unroll
    for (int rg = 0; rg < 4; ++rg)
      tq[qs][rg] = ts[n * SEQ + q0 + qs * 16 + quad * 4 + rg] * c2;
  }

  f32x4 accO[2][4] = {};
  f32x4 accL[2] = {};
  bf16x8 ones_b;
  {
    union { uint16_t u[8]; bf16x8 v; } t;
    uint16_t o = (l16 == 0) ? 0x3F80 : 0;   // bf16 1.0 in column 0 only
#pragma unroll
    for (int j = 0; j < 8; ++j) t.u[j] = o;
    ones_b = t.v;
  }
  uint16_t* Pw = &Plds[w][0];

  const uint16_t* Kbase = QKV + rowbase + DM + h * DH;
  const uint16_t* Vbase = QKV + rowbase + 2 * DM + h * DH;
  const int vr = tid & 63, vdb = (tid >> 6) * 8;   // 8 d-cols per thread
  const int kr = tid >> 3, kc = (tid & 7) ^ swz(tid >> 3);
  uint4 vreg0;

  // prologue: stage tile 0 (K via gload_lds one-shot, V via regs)
  async16(&Klds[0][wu * 64 * 8], Kbase + (size_t)kr * NQKV + kc * 8);
  vreg0 = *(const uint4*)(Vbase + (size_t)vr * NQKV + vdb);
  __syncthreads();                           // vmcnt drained: K0 in LDS, V0 in regs
  {
    union { uint4 v; uint16_t u[8]; } a0;
    a0.v = vreg0;
#pragma unroll
    for (int j = 0; j < 8; ++j) Vt[(vdb + j) * 72 + vr] = a0.u[j];
  }
  __syncthreads();                           // tile 0 ready

  for (int it = 0; it < 8; ++it) {
    const int k0 = it * 64, cur = it & 1;
    // prefetch tile it+1 BEFORE compute: K async into the other buffer, V to regs
    if (it < 7) {
      async16(&Klds[cur ^ 1][wu * 64 * 8],
              Kbase + (size_t)(k0 + 64 + kr) * NQKV + kc * 8);
      vreg0 = *(const uint4*)(Vbase + (size_t)(k0 + 64 + vr) * NQKV + vdb);
    }

#pragma unroll
    for (int kt = 0; kt < 2; ++kt) {
      uint16_t* Pk = Pw + kt * 1280;         // kt-indexed: cross-kt disjoint
      // S = Q K^T over this 32-col k-tile; columns interleaved: n -> k = 2*(lane&15)+ksu
      f32x4 s[2][2] = {};
      __builtin_amdgcn_s_setprio(1);
#pragma unroll
      for (int dsp = 0; dsp < 2; ++dsp) {
        bf16x8 kf[2];
#pragma unroll
        for (int ksu = 0; ksu < 2; ++ksu) {
          int r = kt * 32 + 2 * l16 + ksu;
          int c = (dsp * 4 + quad) ^ swz(r);
          kf[ksu] = *(const bf16x8*)&Klds[cur][r * 64 + c * 8];
        }
#pragma unroll
        for (int qs = 0; qs < 2; ++qs)
#pragma unroll
          for (int ksu = 0; ksu < 2; ++ksu)
            s[qs][ksu] = MFMA16(qf[qs][dsp], kf[ksu], s[qs][ksu]);
      }
      __builtin_amdgcn_s_setprio(0);
      // bias + exp + pack to bf16 pairs -> Pk[q][k] (natural k order)
      float tk0 = tkl[k0 + kt * 32 + 2 * l16];
      float tk1 = tkl[k0 + kt * 32 + 2 * l16 + 1];
#pragma unroll
      for (int qs = 0; qs < 2; ++qs) {
#pragma unroll
        for (int rg = 0; rg < 4; ++rg) {
          float d0 = fabsf(tq[qs][rg] - tk0);   // v_sub; abs/neg ride as fma modifiers
          float d1 = fabsf(tq[qs][rg] - tk1);
          float p0 = __builtin_amdgcn_exp2f(fmaf(s[qs][0][rg], c1, -d0));
          float p1 = __builtin_amdgcn_exp2f(fmaf(s[qs][1][rg], c1, -d1));
          uint32_t u = (__float_as_uint(p0) >> 16) | (__float_as_uint(p1) & 0xFFFF0000u);
          *(uint32_t*)(Pk + (qs * 16 + quad * 4 + rg) * 40 + 2 * l16) = u;
        }
      }
      // PV (+ ones column for row-sums). Wave-private LDS: may-alias keeps the
      // P write->read order; DS pipe is in-order per wave (R0-proven, no fence).
      bf16x8 vb[4];
#pragma unroll
      for (int dt = 0; dt < 4; ++dt)
        vb[dt] = *(const bf16x8*)&Vt[(dt * 16 + l16) * 72 + kt * 32 + quad * 8];
      __builtin_amdgcn_s_setprio(1);
#pragma unroll
      for (int qs = 0; qs < 2; ++qs) {
        bf16x8 pa = *(const bf16x8*)(Pk + (qs * 16 + l16) * 40 + quad * 8);
#pragma unroll
        for (int dt = 0; dt < 4; ++dt)
          accO[qs][dt] = MFMA16(pa, vb[dt], accO[qs][dt]);
        accL[qs] = MFMA16(pa, ones_b, accL[qs]);
      }
      __builtin_amdgcn_s_setprio(0);
    }

    __syncthreads();                 // reads of Klds[cur]/Vt done; vmcnt drained (K/V it+1 ready)
    if (it < 7) {
      union { uint4 v; uint16_t u[8]; } a0;
      a0.v = vreg0;
#pragma unroll
      for (int j = 0; j < 8; ++j) Vt[(vdb + j) * 72 + vr] = a0.u[j];
    }
    __syncthreads();                 // Vt(it+1) ready; Klds[cur^1] ready
  }
  // epilogue: O = accO / l ; l lives in column 0 (lane quad*16) of accL
#pragma unroll
  for (int qs = 0; qs < 2; ++qs) {
    float inv[4];
#pragma unroll
    for (int rg = 0; rg < 4; ++rg) {
      float lv = __shfl(accL[qs][rg], lane & 48, 64);
      inv[rg] = 1.0f / lv;
    }
#pragma unroll
    for (int dt = 0; dt < 4; ++dt) {
#pragma unroll
      for (int rg = 0; rg < 4; ++rg) {
        int qr = q0 + qs * 16 + quad * 4 + rg;
        float v = accO[qs][dt][rg] * inv[rg];
        Aout[(size_t)(n * SEQ + qr) * DM + h * DH + dt * 16 + l16] = f2bf(v);
      }
    }
  }
}

// ---------------- readout pooling (unchanged) ----------------
__global__ __launch_bounds__(256) void k_pool(
    const uint16_t* __restrict__ Out, const float* __restrict__ mask,
    const float* __restrict__ readout, float* __restrict__ dst) {
  __shared__ float rsl[64];
  __shared__ float ex[SEQ];
  __shared__ float red[4];
  __shared__ float part[8][64];
  int b = blockIdx.x;
  int n = b / NH, h = b % NH;
  int tid = threadIdx.x;
  if (tid < 64) rsl[tid] = readout[h * DH + tid];
  __syncthreads();

  float suml = 0.f;
  for (int l = tid; l < SEQ; l += 256) {
    const uint16_t* rowp = Out + (size_t)(n * SEQ + l) * DM + h * DH;
    float acc = 0.f;
#pragma unroll
    for (int c = 0; c < 8; ++c) {
      union { uint4 v; uint16_t u[8]; } t;
      t.v = *(const uint4*)(rowp + c * 8);
#pragma unroll
      for (int j = 0; j < 8; ++j)
        acc += __uint_as_float(((uint32_t)t.u[j]) << 16) * rsl[c * 8 + j];
    }
    float e = __builtin_amdgcn_exp2f(acc * (0.125f * 1.44269504f));
    e = (mask[n * SEQ + l] > 0.f) ? e : 0.f;
    ex[l] = e;
    suml += e;
  }
#pragma unroll
  for (int off = 32; off; off >>= 1) suml += __shfl_down(suml, off, 64);
  if ((tid & 63) == 0) red[tid >> 6] = suml;
  __syncthreads();
  float inv = 1.0f / (red[0] + red[1] + red[2] + red[3]);

  int d0 = (tid & 31) * 2, ch = tid >> 5;
  float a0 = 0.f, a1 = 0.f;
  for (int l = ch * 64; l < ch * 64 + 64; ++l) {
    uint32_t pv = *(const uint32_t*)(Out + (size_t)(n * SEQ + l) * DM + h * DH + d0);
    float e = ex[l];
    a0 = fmaf(__uint_as_float(pv << 16), e, a0);
    a1 = fmaf(__uint_as_float(pv & 0xFFFF0000u), e, a1);
  }
  part[ch][d0] = a0;
  part[ch][d0 + 1] = a1;
  __syncthreads();
  if (tid < 64) {
    float s = 0.f;
#pragma unroll
    for (int c = 0; c < 8; ++c) s += part[c][tid];
    dst[n * DM + h * DH + tid] = s * inv;
  }
}

// ---------------- launch ----------------
extern "C" void kernel_launch(void* const* d_in, const int* in_sizes, int n_in,
                              void* d_out, int out_size, void* d_ws, size_t ws_size,
                              hipStream_t stream) {
  const float* tokens  = (const float*)d_in[0];
  const float* ts      = (const float*)d_in[1];
  const float* mask    = (const float*)d_in[2];
  const float* Wq      = (const float*)d_in[3];
  const float* bq      = (const float*)d_in[4];
  const float* Wk      = (const float*)d_in[5];
  const float* bk      = (const float*)d_in[6];
  const float* Wv      = (const float*)d_in[7];
  const float* bv      = (const float*)d_in[8];
  const float* Wo      = (const float*)d_in[9];
  const float* bo      = (const float*)d_in[10];
  const float* readout = (const float*)d_in[11];

  char* ws = (char*)d_ws;
  uint16_t* X    = (uint16_t*)ws;                   // 50,331,648 B ; reused as attn_out
  uint16_t* Wqkv = (uint16_t*)(ws + 50331648);      //  3,538,944 B (packed)
  uint16_t* Wob  = (uint16_t*)(ws + 53870592);      //  1,179,648 B (packed)
  float*    bqkv = (float*)   (ws + 55050240);      //      9,216 B
  uint16_t* QKV  = (uint16_t*)(ws + 55059456);      // 150,994,944 B ; reused as Out
  uint16_t* attn = X;
  uint16_t* Outb = QKV;

  k_cvt<<<12288, 256, 0, stream>>>(tokens, Wq, Wk, Wv, Wo, bq, bk, bv, X, Wqkv, Wob, bqkv);
  k_gemm_bt<<<4608, 256, 0, stream>>>(X, Wqkv, bqkv, nullptr, QKV, NQKV, 18);
  k_attn<<<1536, 512, 0, stream>>>(QKV, ts, mask, attn);
  k_gemm_bt<<<1536, 256, 0, stream>>>(attn, Wob, bo, mask, Outb, DM, 6);
  k_pool<<<768, 256, 0, stream>>>(Outb, mask, readout, (float*)d_out);
}